// Round 11
// baseline (212.358 us; speedup 1.0000x reference)
//
#include <hip/hip_runtime.h>
#include <hip/hip_bf16.h>

// Problem constants
#define SEQ   2048
#define INF_  512          // IN dim
#define HQ    16           // query heads
#define KVH   4            // kv heads
#define DH    64           // head dim
#define NQ    (HQ*DH)      // 1024
#define NKV   (KVH*DH)     // 256
#define OUTD  512

typedef short v8s __attribute__((ext_vector_type(8)));   // 8 bf16 (4 VGPRs)
typedef float v4f __attribute__((ext_vector_type(4)));   // 4 fp32 acc

static __device__ __forceinline__ float bf2f(unsigned short u) {
    union { unsigned int i; float f; } c;
    c.i = ((unsigned int)u) << 16;
    return c.f;
}
static __device__ __forceinline__ unsigned short f2bf(float f) {  // RNE
    union { float f; unsigned int i; } c; c.f = f;
    unsigned int lsb = (c.i >> 16) & 1u;
    c.i += 0x7fffu + lsb;
    return (unsigned short)(c.i >> 16);
}
static __device__ __forceinline__ unsigned int f2bf2(float lo, float hi) { // packed cvt
    union { __hip_bfloat162 h; unsigned int u; } c;
    c.h = __float22bfloat162_rn(make_float2(lo, hi));
    return c.u;
}
// pack two v4f (8 fp32) into one bf16x8 fragment
static __device__ __forceinline__ v8s pack8(v4f a, v4f b) {
    union { v8s s; uint4 u; } c;
    c.u = make_uint4(f2bf2(a[0], a[1]), f2bf2(a[2], a[3]),
                     f2bf2(b[0], b[1]), f2bf2(b[2], b[3]));
    return c.s;
}

// async global->LDS DMA, 16B per lane; lds base must be lane-invariant
static __device__ __forceinline__ void gll16(const void* g, void* l) {
    __builtin_amdgcn_global_load_lds(
        (const __attribute__((address_space(1))) void*)g,
        (__attribute__((address_space(3))) void*)l, 16, 0, 0);
}

#define QSCALE 0.180336880f   // 0.125 * log2(e): scores in log2 domain -> exp2

// ===========================================================================
// GEMM 1 (MFMA): QKV projection, fp32 in -> bf16 swizzled tile buffers.
// 64x64 tile, BK=64, DEPTH-2 register prefetch. Grid 32x24 = 768 blocks.
// Tile formats (4096 elems): Qg[t][h], Kg[g][t]: row r, elem at
//   r*64 + ((d>>3)^(r&7))*8 + (d&7).   Q pre-scaled by QSCALE.
// Vg[g][t]: row d, value V^T[d][j] stored at permuted position
//   p = (j&32) + ((j>>2)&3)*8 + ((j>>4)&1)*4 + (j&3), group-swizzled by d&7.
// ===========================================================================
__global__ __launch_bounds__(256, 3) void gemm_qkv(
    const float* __restrict__ x,
    const float* __restrict__ Wq,
    const float* __restrict__ Wk,
    const float* __restrict__ Wv,
    unsigned short* __restrict__ Qg,
    unsigned short* __restrict__ Kg,
    unsigned short* __restrict__ Vg)
{
    __shared__ unsigned short Asb[64][72];
    __shared__ unsigned short Bsb[64][72];

    const int m0 = blockIdx.x * 64;
    const int n0 = blockIdx.y * 64;

    const float* Bp; int role;   // 0=Q 1=K 2=V
    if (n0 < NQ)            { Bp = Wq + (size_t)n0 * INF_;              role = 0; }
    else if (n0 < NQ + NKV) { Bp = Wk + (size_t)(n0 - NQ) * INF_;       role = 1; }
    else                    { Bp = Wv + (size_t)(n0 - NQ - NKV) * INF_; role = 2; }

    const int tid = threadIdx.x;
    const int w = tid >> 6, lane = tid & 63;
    const int n = lane & 15, quad = lane >> 4;
    const int r0w = (w & 1) * 32, c0w = (w >> 1) * 32;
    const int sr = tid >> 2, skc = (tid & 3) * 16;

    v4f acc[2][2];
#pragma unroll
    for (int rt = 0; rt < 2; rt++)
#pragma unroll
        for (int ct = 0; ct < 2; ct++) acc[rt][ct] = (v4f){0.f,0.f,0.f,0.f};

    const float* ap = x  + (size_t)(m0 + sr) * INF_ + skc;
    const float* bp = Bp + (size_t)sr * INF_ + skc;

    float4 pa[2][4], pb[2][4];   // depth-2 slab prefetch
#pragma unroll
    for (int s = 0; s < 2; s++)
#pragma unroll
        for (int i = 0; i < 4; i++) {
            pa[s][i] = *(const float4*)(ap + s * 64 + 4 * i);
            pb[s][i] = *(const float4*)(bp + s * 64 + 4 * i);
        }

    for (int kb = 0; kb < INF_; kb += 64) {
        const int s = (kb >> 6) & 1;
        __syncthreads();
        *(uint4*)&Asb[sr][skc]     = make_uint4(f2bf2(pa[s][0].x,pa[s][0].y), f2bf2(pa[s][0].z,pa[s][0].w),
                                                f2bf2(pa[s][1].x,pa[s][1].y), f2bf2(pa[s][1].z,pa[s][1].w));
        *(uint4*)&Asb[sr][skc + 8] = make_uint4(f2bf2(pa[s][2].x,pa[s][2].y), f2bf2(pa[s][2].z,pa[s][2].w),
                                                f2bf2(pa[s][3].x,pa[s][3].y), f2bf2(pa[s][3].z,pa[s][3].w));
        *(uint4*)&Bsb[sr][skc]     = make_uint4(f2bf2(pb[s][0].x,pb[s][0].y), f2bf2(pb[s][0].z,pb[s][0].w),
                                                f2bf2(pb[s][1].x,pb[s][1].y), f2bf2(pb[s][1].z,pb[s][1].w));
        *(uint4*)&Bsb[sr][skc + 8] = make_uint4(f2bf2(pb[s][2].x,pb[s][2].y), f2bf2(pb[s][2].z,pb[s][2].w),
                                                f2bf2(pb[s][3].x,pb[s][3].y), f2bf2(pb[s][3].z,pb[s][3].w));
        __syncthreads();
        if (kb + 128 < INF_) {
#pragma unroll
            for (int i = 0; i < 4; i++) {
                pa[s][i] = *(const float4*)(ap + kb + 128 + 4 * i);
                pb[s][i] = *(const float4*)(bp + kb + 128 + 4 * i);
            }
        }
#pragma unroll
        for (int kk = 0; kk < 2; kk++) {
            v8s a0 = *(const v8s*)&Asb[r0w + n][kk * 32 + quad * 8];
            v8s a1 = *(const v8s*)&Asb[r0w + 16 + n][kk * 32 + quad * 8];
            v8s b0 = *(const v8s*)&Bsb[c0w + n][kk * 32 + quad * 8];
            v8s b1 = *(const v8s*)&Bsb[c0w + 16 + n][kk * 32 + quad * 8];
            acc[0][0] = __builtin_amdgcn_mfma_f32_16x16x32_bf16(a0, b0, acc[0][0], 0, 0, 0);
            acc[0][1] = __builtin_amdgcn_mfma_f32_16x16x32_bf16(a0, b1, acc[0][1], 0, 0, 0);
            acc[1][0] = __builtin_amdgcn_mfma_f32_16x16x32_bf16(a1, b0, acc[1][0], 0, 0, 0);
            acc[1][1] = __builtin_amdgcn_mfma_f32_16x16x32_bf16(a1, b1, acc[1][1], 0, 0, 0);
        }
    }

    const int t = m0 >> 6;
    if (role == 0) {
        unsigned short* base = Qg + ((size_t)(t * 16 + (n0 >> 6))) * 4096;
#pragma unroll
        for (int rt = 0; rt < 2; rt++)
#pragma unroll
            for (int ct = 0; ct < 2; ct++)
#pragma unroll
                for (int reg = 0; reg < 4; reg++) {
                    const int r = r0w + rt * 16 + quad * 4 + reg;
                    const int d = c0w + ct * 16 + n;
                    base[r * 64 + (((d >> 3) ^ (r & 7)) * 8) + (d & 7)] =
                        f2bf(acc[rt][ct][reg] * QSCALE);
                }
    } else if (role == 1) {
        const int g = (n0 - NQ) >> 6;
        unsigned short* base = Kg + ((size_t)(g * 32 + t)) * 4096;
#pragma unroll
        for (int rt = 0; rt < 2; rt++)
#pragma unroll
            for (int ct = 0; ct < 2; ct++)
#pragma unroll
                for (int reg = 0; reg < 4; reg++) {
                    const int r = r0w + rt * 16 + quad * 4 + reg;
                    const int d = c0w + ct * 16 + n;
                    base[r * 64 + (((d >> 3) ^ (r & 7)) * 8) + (d & 7)] =
                        f2bf(acc[rt][ct][reg]);
                }
    } else {
        const int g = (n0 - NQ - NKV) >> 6;
        unsigned short* base = Vg + ((size_t)(g * 32 + t)) * 4096;
#pragma unroll
        for (int rt = 0; rt < 2; rt++)
#pragma unroll
            for (int ct = 0; ct < 2; ct++) {
                const int jb_ = r0w + rt * 16 + quad * 4;  // 4 consecutive j
                const int d = c0w + ct * 16 + n;
                const int p = (jb_ & 32) + (((jb_ >> 2) & 3) * 8) + (((jb_ >> 4) & 1) * 4);
                *(uint2*)&base[d * 64 + (((p >> 3) ^ (d & 7)) * 8) + (p & 7)] =
                    make_uint2(f2bf2(acc[rt][ct][0], acc[rt][ct][1]),
                               f2bf2(acc[rt][ct][2], acc[rt][ct][3]));
            }
    }
}

// ===========================================================================
// MFMA flash attention, S^T form, max-free exp2 softmax, NO P round-trip:
// j-permuted PV makes QK C-layout registers directly the P^T B-fragments.
// Block = (128 q-rows, head, ONE kv head g); 1024 blocks, 4/CU co-resident.
// LDS 16KB (K/V dbufs only); Q frags read direct from global.
// ===========================================================================
__global__ __launch_bounds__(256, 4) void attn_mfma(
    const unsigned short* __restrict__ Qg,
    const unsigned short* __restrict__ Kg,
    const unsigned short* __restrict__ Vg,
    unsigned short* __restrict__ Oh)      // 4 planes of SEQ*NQ bf16
{
    __shared__ unsigned short Ksb[2][4096];
    __shared__ unsigned short Vsb[2][4096];

    const int bx = blockIdx.x;
    const int h  = bx & 15;
    const int jj = (bx >> 4) & 15;
    const int g  = bx >> 8;                          // 0..3 (dispatch round)
    const int jj2 = (jj + 8 * (g >> 1)) & 15;        // stagger rounds 2,3
    const int qi2 = (g & 1) ? (15 - jj2) : jj2;      // complementary pairing
    const int q0 = qi2 * 128;
    const int tid = threadIdx.x;
    const int w = tid >> 6, lane = tid & 63;
    const int n = lane & 15, quad = lane >> 4;
    const int r0 = w * 32;
    const int m7 = n & 7;
    const int ntile = 2 * qi2 + 2;

    // DMA K/V tile 0
    {
        const size_t off = ((size_t)(g * 32)) * 4096 + w * 1024 + lane * 8;
        gll16(Kg + off,       &Ksb[0][w * 1024]);
        gll16(Kg + off + 512, &Ksb[0][w * 1024 + 512]);
        gll16(Vg + off,       &Vsb[0][w * 1024]);
        gll16(Vg + off + 512, &Vsb[0][w * 1024 + 512]);
    }

    // Q B-frags direct from global (Qg pre-scaled by QSCALE)
    v8s qf[2][2];
    {
        const unsigned short* tb =
            Qg + ((size_t)((2 * qi2 + (r0 >> 6)) * 16 + h)) * 4096 + (r0 & 63) * 64;
#pragma unroll
        for (int qt = 0; qt < 2; qt++) {
            const unsigned short* rp = tb + (qt * 16 + n) * 64;
            qf[qt][0] = *(const v8s*)(rp + (quad ^ m7) * 8);
            qf[qt][1] = *(const v8s*)(rp + ((quad + 4) ^ m7) * 8);
        }
    }

    float lst[2] = {0.f, 0.f};
    v4f Oacc[2][4];
#pragma unroll
    for (int qt = 0; qt < 2; qt++)
#pragma unroll
        for (int dt = 0; dt < 4; dt++) Oacc[qt][dt] = (v4f){0.f,0.f,0.f,0.f};
    const v4f z = (v4f){0.f,0.f,0.f,0.f};

    for (int tt = 0; tt < ntile; tt++) {
        const int buf = tt & 1;
        __syncthreads();   // drains this wave's DMA; protects buf^1 overwrite
        if (tt + 1 < ntile) {
            const size_t off = ((size_t)(g * 32 + tt + 1)) * 4096 + w * 1024 + lane * 8;
            const int nb = buf ^ 1;
            gll16(Kg + off,       &Ksb[nb][w * 1024]);
            gll16(Kg + off + 512, &Ksb[nb][w * 1024 + 512]);
            gll16(Vg + off,       &Vsb[nb][w * 1024]);
            gll16(Vg + off + 512, &Vsb[nb][w * 1024 + 512]);
        }
        const int t0 = tt * 64;
        const bool do0 = (t0 <= q0 + r0 + 15);
        const bool do1 = (t0 <= q0 + r0 + 31);
        if (!do1) continue;

        const unsigned short* Kb = Ksb[buf];
        const unsigned short* Vb = Vsb[buf];

        // S^T = K·Q^T (C-layout: lane holds q=n, j = jt*16+quad*4+reg)
        v4f sc[2][4];
#pragma unroll
        for (int jt = 0; jt < 4; jt++) {
            const int kr = (jt * 16 + n) * 64;
            v8s kf0 = *(const v8s*)&Kb[kr + (quad ^ m7) * 8];
            v8s kf1 = *(const v8s*)&Kb[kr + ((quad + 4) ^ m7) * 8];
            if (do0) {
                v4f tq = __builtin_amdgcn_mfma_f32_16x16x32_bf16(kf0, qf[0][0], z, 0, 0, 0);
                sc[0][jt] = __builtin_amdgcn_mfma_f32_16x16x32_bf16(kf1, qf[0][1], tq, 0, 0, 0);
            }
            v4f t1 = __builtin_amdgcn_mfma_f32_16x16x32_bf16(kf0, qf[1][0], z, 0, 0, 0);
            sc[1][jt] = __builtin_amdgcn_mfma_f32_16x16x32_bf16(kf1, qf[1][1], t1, 0, 0, 0);
        }

        // mask (diagonal region only) + exp2 + per-lane l
#pragma unroll
        for (int qt = 0; qt < 2; qt++) {
            if (qt == 0 && !do0) continue;
            const int qg = q0 + r0 + qt * 16 + n;
            if (t0 + 63 > q0 + r0 + qt * 16) {
#pragma unroll
                for (int jt = 0; jt < 4; jt++) {
                    const int jg = t0 + jt * 16 + quad * 4;
#pragma unroll
                    for (int reg = 0; reg < 4; reg++)
                        sc[qt][jt][reg] = (jg + reg <= qg) ? sc[qt][jt][reg] : -INFINITY;
                }
            }
#pragma unroll
            for (int jt = 0; jt < 4; jt++) {
#pragma unroll
                for (int reg = 0; reg < 4; reg++) {
                    float p = __builtin_amdgcn_exp2f(sc[qt][jt][reg]);  // 2^-inf = 0
                    sc[qt][jt][reg] = p;
                    lst[qt] += p;
                }
            }
        }

        // P^T B-frags = C-layout registers (j-permuted PV; no LDS/shuffle)
        v8s pf[2][2];
        if (do0) {
            pf[0][0] = pack8(sc[0][0], sc[0][1]);
            pf[0][1] = pack8(sc[0][2], sc[0][3]);
        }
        pf[1][0] = pack8(sc[1][0], sc[1][1]);
        pf[1][1] = pack8(sc[1][2], sc[1][3]);

        // PV: O^T += V^T(permuted) · P^T
#pragma unroll
        for (int dt = 0; dt < 4; dt++) {
            const int vr = (dt * 16 + n) * 64;
            v8s vf0 = *(const v8s*)&Vb[vr + (quad ^ m7) * 8];
            v8s vf1 = *(const v8s*)&Vb[vr + ((quad + 4) ^ m7) * 8];
            if (do0) {
                Oacc[0][dt] = __builtin_amdgcn_mfma_f32_16x16x32_bf16(vf0, pf[0][0], Oacc[0][dt], 0, 0, 0);
                Oacc[0][dt] = __builtin_amdgcn_mfma_f32_16x16x32_bf16(vf1, pf[0][1], Oacc[0][dt], 0, 0, 0);
            }
            Oacc[1][dt] = __builtin_amdgcn_mfma_f32_16x16x32_bf16(vf0, pf[1][0], Oacc[1][dt], 0, 0, 0);
            Oacc[1][dt] = __builtin_amdgcn_mfma_f32_16x16x32_bf16(vf1, pf[1][1], Oacc[1][dt], 0, 0, 0);
        }
    }

    // normalize (l per lane; reduce across 4 quads) & store bf16
    unsigned short* Ohp = Oh + (size_t)g * ((size_t)SEQ * NQ);
#pragma unroll
    for (int qt = 0; qt < 2; qt++) {
        float L = lst[qt];
        L += __shfl_xor(L, 16);
        L += __shfl_xor(L, 32);
        const float inv = 0.25f / L;   // j=0 always unmasked -> L>0
        const int row = q0 + r0 + qt * 16 + n;
        unsigned short* dst = Ohp + (size_t)row * NQ + h * DH + quad * 4;
#pragma unroll
        for (int dt = 0; dt < 4; dt++) {
            uint2 pk = make_uint2(f2bf2(Oacc[qt][dt][0] * inv, Oacc[qt][dt][1] * inv),
                                  f2bf2(Oacc[qt][dt][2] * inv, Oacc[qt][dt][3] * inv));
            *(uint2*)(dst + dt * 16) = pk;
        }
    }
}

// ===========================================================================
// GEMM 2 (MFMA): out[s][o] = sum_j (sum_g Oh[g])[s][j] * Wo[o][j]. fp32 out.
// 64x64 tile, BK=64, depth-2 prefetch. Grid 32x8 = 256 blocks.
// ===========================================================================
__global__ __launch_bounds__(256) void gemm_out(
    const unsigned short* __restrict__ Oh,
    const float* __restrict__ Wo,
    float* __restrict__ C)
{
    __shared__ unsigned short Asb[64][72];
    __shared__ unsigned short Bsb[64][72];

    const int m0 = blockIdx.x * 64;
    const int n0 = blockIdx.y * 64;
    const int tid = threadIdx.x;
    const int w = tid >> 6, lane = tid & 63;
    const int n = lane & 15, quad = lane >> 4;
    const int r0w = (w & 1) * 32, c0w = (w >> 1) * 32;
    const int sr = tid >> 2, skc = (tid & 3) * 16;

    v4f acc[2][2];
#pragma unroll
    for (int rt = 0; rt < 2; rt++)
#pragma unroll
        for (int ct = 0; ct < 2; ct++) acc[rt][ct] = (v4f){0.f,0.f,0.f,0.f};

    const size_t abase = (size_t)(m0 + sr) * NQ + skc;
    const float* bp = Wo + (size_t)(n0 + sr) * NQ + skc;
    const size_t plane = (size_t)SEQ * NQ;

    uint4 ua[2][4][2];            // [slab][gplane][half]
    float4 pb[2][4];
#pragma unroll
    for (int s = 0; s < 2; s++) {
#pragma unroll
        for (int gpl = 0; gpl < 4; gpl++) {
            const unsigned short* p = Oh + gpl * plane + abase + s * 64;
            ua[s][gpl][0] = *(const uint4*)(p);
            ua[s][gpl][1] = *(const uint4*)(p + 8);
        }
#pragma unroll
        for (int i = 0; i < 4; i++) pb[s][i] = *(const float4*)(bp + s * 64 + 4 * i);
    }

    for (int kb = 0; kb < NQ; kb += 64) {
        const int s = (kb >> 6) & 1;
        __syncthreads();
        // A staging: fp32-accurate 4-plane sum, then single bf16 rounding
#pragma unroll
        for (int hf = 0; hf < 2; hf++) {
            unsigned int outw[4];
#pragma unroll
            for (int q = 0; q < 4; q++) {
                const unsigned int u0 = ((const unsigned int*)&ua[s][0][hf])[q];
                const unsigned int u1 = ((const unsigned int*)&ua[s][1][hf])[q];
                const unsigned int u2 = ((const unsigned int*)&ua[s][2][hf])[q];
                const unsigned int u3 = ((const unsigned int*)&ua[s][3][hf])[q];
                float lo = bf2f((unsigned short)(u0 & 0xffffu)) + bf2f((unsigned short)(u1 & 0xffffu))
                         + bf2f((unsigned short)(u2 & 0xffffu)) + bf2f((unsigned short)(u3 & 0xffffu));
                float hi = bf2f((unsigned short)(u0 >> 16)) + bf2f((unsigned short)(u1 >> 16))
                         + bf2f((unsigned short)(u2 >> 16)) + bf2f((unsigned short)(u3 >> 16));
                outw[q] = f2bf2(lo, hi);
            }
            *(uint4*)&Asb[sr][skc + hf * 8] = make_uint4(outw[0], outw[1], outw[2], outw[3]);
        }
        *(uint4*)&Bsb[sr][skc]     = make_uint4(f2bf2(pb[s][0].x,pb[s][0].y), f2bf2(pb[s][0].z,pb[s][0].w),
                                                f2bf2(pb[s][1].x,pb[s][1].y), f2bf2(pb[s][1].z,pb[s][1].w));
        *(uint4*)&Bsb[sr][skc + 8] = make_uint4(f2bf2(pb[s][2].x,pb[s][2].y), f2bf2(pb[s][2].z,pb[s][2].w),
                                                f2bf2(pb[s][3].x,pb[s][3].y), f2bf2(pb[s][3].z,pb[s][3].w));
        __syncthreads();
        if (kb + 128 < NQ) {
#pragma unroll
            for (int gpl = 0; gpl < 4; gpl++) {
                const unsigned short* p = Oh + gpl * plane + abase + kb + 128;
                ua[s][gpl][0] = *(const uint4*)(p);
                ua[s][gpl][1] = *(const uint4*)(p + 8);
            }
#pragma unroll
            for (int i = 0; i < 4; i++) pb[s][i] = *(const float4*)(bp + kb + 128 + 4 * i);
        }
#pragma unroll
        for (int kk = 0; kk < 2; kk++) {
            v8s a0 = *(const v8s*)&Asb[r0w + n][kk * 32 + quad * 8];
            v8s a1 = *(const v8s*)&Asb[r0w + 16 + n][kk * 32 + quad * 8];
            v8s b0 = *(const v8s*)&Bsb[c0w + n][kk * 32 + quad * 8];
            v8s b1 = *(const v8s*)&Bsb[c0w + 16 + n][kk * 32 + quad * 8];
            acc[0][0] = __builtin_amdgcn_mfma_f32_16x16x32_bf16(a0, b0, acc[0][0], 0, 0, 0);
            acc[0][1] = __builtin_amdgcn_mfma_f32_16x16x32_bf16(a0, b1, acc[0][1], 0, 0, 0);
            acc[1][0] = __builtin_amdgcn_mfma_f32_16x16x32_bf16(a1, b0, acc[1][0], 0, 0, 0);
            acc[1][1] = __builtin_amdgcn_mfma_f32_16x16x32_bf16(a1, b1, acc[1][1], 0, 0, 0);
        }
    }

#pragma unroll
    for (int rt = 0; rt < 2; rt++)
#pragma unroll
        for (int ct = 0; ct < 2; ct++)
#pragma unroll
            for (int reg = 0; reg < 4; reg++) {
                const int row = m0 + r0w + rt * 16 + quad * 4 + reg;
                const int col = n0 + c0w + ct * 16 + n;
                C[(size_t)row * OUTD + col] = acc[rt][ct][reg];
            }
}

// ===========================================================================
extern "C" void kernel_launch(void* const* d_in, const int* in_sizes, int n_in,
                              void* d_out, int out_size, void* d_ws, size_t ws_size,
                              hipStream_t stream) {
    const float* x  = (const float*)d_in[0];
    const float* Wq = (const float*)d_in[1];
    const float* Wk = (const float*)d_in[2];
    const float* Wv = (const float*)d_in[3];
    const float* Wo = (const float*)d_in[4];
    float* out = (float*)d_out;

    // ws: Qg 4MB @0; Kg 1MB @4M; Vg 1MB @5M; Oh 4 planes x 4MB @6M (22MB total)
    char* base = (char*)d_ws;
    unsigned short* Qg = (unsigned short*)(base);
    unsigned short* Kg = (unsigned short*)(base + 4194304);
    unsigned short* Vg = (unsigned short*)(base + 5242880);
    unsigned short* Oh = (unsigned short*)(base + 6291456);

    dim3 blk(256);
    gemm_qkv<<<dim3(SEQ / 64, (NQ + 2 * NKV) / 64), blk, 0, stream>>>(x, Wq, Wk, Wv, Qg, Kg, Vg);
    attn_mfma<<<dim3(1024), blk, 0, stream>>>(Qg, Kg, Vg, Oh);
    gemm_out<<<dim3(SEQ / 64, OUTD / 64), blk, 0, stream>>>(Oh, Wo, out);
}

// Round 12
// 155.571 us; speedup vs baseline: 1.3650x; 1.3650x over previous
//
#include <hip/hip_runtime.h>
#include <hip/hip_bf16.h>

// Problem constants
#define SEQ   2048
#define INF_  512          // IN dim
#define HQ    16           // query heads
#define KVH   4            // kv heads
#define DH    64           // head dim
#define NQ    (HQ*DH)      // 1024
#define NKV   (KVH*DH)     // 256
#define OUTD  512

typedef short v8s __attribute__((ext_vector_type(8)));   // 8 bf16 (4 VGPRs)
typedef float v4f __attribute__((ext_vector_type(4)));   // 4 fp32 acc

static __device__ __forceinline__ float bf2f(unsigned short u) {
    union { unsigned int i; float f; } c;
    c.i = ((unsigned int)u) << 16;
    return c.f;
}
static __device__ __forceinline__ unsigned short f2bf(float f) {  // RNE
    union { float f; unsigned int i; } c; c.f = f;
    unsigned int lsb = (c.i >> 16) & 1u;
    c.i += 0x7fffu + lsb;
    return (unsigned short)(c.i >> 16);
}
static __device__ __forceinline__ unsigned int f2bf2(float lo, float hi) { // packed cvt
    union { __hip_bfloat162 h; unsigned int u; } c;
    c.h = __float22bfloat162_rn(make_float2(lo, hi));
    return c.u;
}
// pack two v4f (8 fp32) into one bf16x8 fragment
static __device__ __forceinline__ v8s pack8(v4f a, v4f b) {
    union { v8s s; uint4 u; } c;
    c.u = make_uint4(f2bf2(a[0], a[1]), f2bf2(a[2], a[3]),
                     f2bf2(b[0], b[1]), f2bf2(b[2], b[3]));
    return c.s;
}

// async global->LDS DMA, 16B per lane; lds base must be lane-invariant
static __device__ __forceinline__ void gll16(const void* g, void* l) {
    __builtin_amdgcn_global_load_lds(
        (const __attribute__((address_space(1))) void*)g,
        (__attribute__((address_space(3))) void*)l, 16, 0, 0);
}

#define QSCALE 0.180336880f   // 0.125 * log2(e): scores in log2 domain -> exp2

// ===========================================================================
// Cast kernel: x/Wq/Wk/Wv/Wo fp32 -> bf16 flat copies. 8 floats/thread,
// 1152 blocks x 256 thr covers exactly 2,359,296 floats (all 8-divisible).
// ===========================================================================
__global__ __launch_bounds__(256) void cast_all(
    const float* __restrict__ x,  const float* __restrict__ Wq,
    const float* __restrict__ Wk, const float* __restrict__ Wv,
    const float* __restrict__ Wo,
    unsigned short* __restrict__ xb,  unsigned short* __restrict__ Wqb,
    unsigned short* __restrict__ Wkb, unsigned short* __restrict__ Wvb,
    unsigned short* __restrict__ Wob)
{
    size_t i = ((size_t)blockIdx.x * 256 + threadIdx.x) * 8;
    const float* s; unsigned short* d; size_t off;
    if (i < 1048576)      { s = x;  d = xb;  off = i; }
    else if (i < 1572864) { s = Wq; d = Wqb; off = i - 1048576; }
    else if (i < 1703936) { s = Wk; d = Wkb; off = i - 1572864; }
    else if (i < 1835008) { s = Wv; d = Wvb; off = i - 1703936; }
    else                  { s = Wo; d = Wob; off = i - 1835008; }
    float4 a = *(const float4*)(s + off);
    float4 b = *(const float4*)(s + off + 4);
    *(uint4*)(d + off) = make_uint4(f2bf2(a.x, a.y), f2bf2(a.z, a.w),
                                    f2bf2(b.x, b.y), f2bf2(b.z, b.w));
}

// ===========================================================================
// GEMM 1 (MFMA): QKV projection, bf16 in -> bf16 swizzled tile buffers.
// 64x64 tile, BK=64, depth-1 uint4 prefetch (no cvt VALU). Grid 32x24.
// Tile formats (4096 elems): Qg[t][h], Kg[g][t]: row r, elem at
//   r*64 + ((d>>3)^(r&7))*8 + (d&7).   Q pre-scaled by QSCALE.
// Vg[g][t]: row d, V^T[d][j] at p = (j&32)+((j>>2)&3)*8+((j>>4)&1)*4+(j&3),
//   group-swizzled by d&7.
// ===========================================================================
__global__ __launch_bounds__(256, 4) void gemm_qkv(
    const unsigned short* __restrict__ xb,
    const unsigned short* __restrict__ Wqb,
    const unsigned short* __restrict__ Wkb,
    const unsigned short* __restrict__ Wvb,
    unsigned short* __restrict__ Qg,
    unsigned short* __restrict__ Kg,
    unsigned short* __restrict__ Vg)
{
    __shared__ unsigned short Asb[64][72];
    __shared__ unsigned short Bsb[64][72];

    const int m0 = blockIdx.x * 64;
    const int n0 = blockIdx.y * 64;

    const unsigned short* Bp; int role;   // 0=Q 1=K 2=V
    if (n0 < NQ)            { Bp = Wqb + (size_t)n0 * INF_;              role = 0; }
    else if (n0 < NQ + NKV) { Bp = Wkb + (size_t)(n0 - NQ) * INF_;       role = 1; }
    else                    { Bp = Wvb + (size_t)(n0 - NQ - NKV) * INF_; role = 2; }

    const int tid = threadIdx.x;
    const int w = tid >> 6, lane = tid & 63;
    const int n = lane & 15, quad = lane >> 4;
    const int r0w = (w & 1) * 32, c0w = (w >> 1) * 32;
    const int sr = tid >> 2, skc = (tid & 3) * 16;

    v4f acc[2][2];
#pragma unroll
    for (int rt = 0; rt < 2; rt++)
#pragma unroll
        for (int ct = 0; ct < 2; ct++) acc[rt][ct] = (v4f){0.f,0.f,0.f,0.f};

    const unsigned short* ap = xb + (size_t)(m0 + sr) * INF_ + skc;
    const unsigned short* bp = Bp + (size_t)sr * INF_ + skc;

    uint4 pa0 = *(const uint4*)(ap),     pa1 = *(const uint4*)(ap + 8);
    uint4 pb0 = *(const uint4*)(bp),     pb1 = *(const uint4*)(bp + 8);

    for (int kb = 0; kb < INF_; kb += 64) {
        __syncthreads();
        *(uint4*)&Asb[sr][skc]     = pa0;
        *(uint4*)&Asb[sr][skc + 8] = pa1;
        *(uint4*)&Bsb[sr][skc]     = pb0;
        *(uint4*)&Bsb[sr][skc + 8] = pb1;
        __syncthreads();
        if (kb + 64 < INF_) {
            pa0 = *(const uint4*)(ap + kb + 64);
            pa1 = *(const uint4*)(ap + kb + 64 + 8);
            pb0 = *(const uint4*)(bp + kb + 64);
            pb1 = *(const uint4*)(bp + kb + 64 + 8);
        }
#pragma unroll
        for (int kk = 0; kk < 2; kk++) {
            v8s a0 = *(const v8s*)&Asb[r0w + n][kk * 32 + quad * 8];
            v8s a1 = *(const v8s*)&Asb[r0w + 16 + n][kk * 32 + quad * 8];
            v8s b0 = *(const v8s*)&Bsb[c0w + n][kk * 32 + quad * 8];
            v8s b1 = *(const v8s*)&Bsb[c0w + 16 + n][kk * 32 + quad * 8];
            acc[0][0] = __builtin_amdgcn_mfma_f32_16x16x32_bf16(a0, b0, acc[0][0], 0, 0, 0);
            acc[0][1] = __builtin_amdgcn_mfma_f32_16x16x32_bf16(a0, b1, acc[0][1], 0, 0, 0);
            acc[1][0] = __builtin_amdgcn_mfma_f32_16x16x32_bf16(a1, b0, acc[1][0], 0, 0, 0);
            acc[1][1] = __builtin_amdgcn_mfma_f32_16x16x32_bf16(a1, b1, acc[1][1], 0, 0, 0);
        }
    }

    const int t = m0 >> 6;
    if (role == 0) {
        unsigned short* base = Qg + ((size_t)(t * 16 + (n0 >> 6))) * 4096;
#pragma unroll
        for (int rt = 0; rt < 2; rt++)
#pragma unroll
            for (int ct = 0; ct < 2; ct++)
#pragma unroll
                for (int reg = 0; reg < 4; reg++) {
                    const int r = r0w + rt * 16 + quad * 4 + reg;
                    const int d = c0w + ct * 16 + n;
                    base[r * 64 + (((d >> 3) ^ (r & 7)) * 8) + (d & 7)] =
                        f2bf(acc[rt][ct][reg] * QSCALE);
                }
    } else if (role == 1) {
        const int g = (n0 - NQ) >> 6;
        unsigned short* base = Kg + ((size_t)(g * 32 + t)) * 4096;
#pragma unroll
        for (int rt = 0; rt < 2; rt++)
#pragma unroll
            for (int ct = 0; ct < 2; ct++)
#pragma unroll
                for (int reg = 0; reg < 4; reg++) {
                    const int r = r0w + rt * 16 + quad * 4 + reg;
                    const int d = c0w + ct * 16 + n;
                    base[r * 64 + (((d >> 3) ^ (r & 7)) * 8) + (d & 7)] =
                        f2bf(acc[rt][ct][reg]);
                }
    } else {
        const int g = (n0 - NQ - NKV) >> 6;
        unsigned short* base = Vg + ((size_t)(g * 32 + t)) * 4096;
#pragma unroll
        for (int rt = 0; rt < 2; rt++)
#pragma unroll
            for (int ct = 0; ct < 2; ct++) {
                const int jb_ = r0w + rt * 16 + quad * 4;  // 4 consecutive j
                const int d = c0w + ct * 16 + n;
                const int p = (jb_ & 32) + (((jb_ >> 2) & 3) * 8) + (((jb_ >> 4) & 1) * 4);
                *(uint2*)&base[d * 64 + (((p >> 3) ^ (d & 7)) * 8) + (p & 7)] =
                    make_uint2(f2bf2(acc[rt][ct][0], acc[rt][ct][1]),
                               f2bf2(acc[rt][ct][2], acc[rt][ct][3]));
            }
    }
}

// ===========================================================================
// MFMA flash attention (unchanged from R11: 77us, 0 bank conflicts).
// ===========================================================================
__global__ __launch_bounds__(256, 4) void attn_mfma(
    const unsigned short* __restrict__ Qg,
    const unsigned short* __restrict__ Kg,
    const unsigned short* __restrict__ Vg,
    unsigned short* __restrict__ Oh)      // 4 planes of SEQ*NQ bf16
{
    __shared__ unsigned short Ksb[2][4096];
    __shared__ unsigned short Vsb[2][4096];

    const int bx = blockIdx.x;
    const int h  = bx & 15;
    const int jj = (bx >> 4) & 15;
    const int g  = bx >> 8;
    const int jj2 = (jj + 8 * (g >> 1)) & 15;
    const int qi2 = (g & 1) ? (15 - jj2) : jj2;
    const int q0 = qi2 * 128;
    const int tid = threadIdx.x;
    const int w = tid >> 6, lane = tid & 63;
    const int n = lane & 15, quad = lane >> 4;
    const int r0 = w * 32;
    const int m7 = n & 7;
    const int ntile = 2 * qi2 + 2;

    {
        const size_t off = ((size_t)(g * 32)) * 4096 + w * 1024 + lane * 8;
        gll16(Kg + off,       &Ksb[0][w * 1024]);
        gll16(Kg + off + 512, &Ksb[0][w * 1024 + 512]);
        gll16(Vg + off,       &Vsb[0][w * 1024]);
        gll16(Vg + off + 512, &Vsb[0][w * 1024 + 512]);
    }

    v8s qf[2][2];
    {
        const unsigned short* tb =
            Qg + ((size_t)((2 * qi2 + (r0 >> 6)) * 16 + h)) * 4096 + (r0 & 63) * 64;
#pragma unroll
        for (int qt = 0; qt < 2; qt++) {
            const unsigned short* rp = tb + (qt * 16 + n) * 64;
            qf[qt][0] = *(const v8s*)(rp + (quad ^ m7) * 8);
            qf[qt][1] = *(const v8s*)(rp + ((quad + 4) ^ m7) * 8);
        }
    }

    float lst[2] = {0.f, 0.f};
    v4f Oacc[2][4];
#pragma unroll
    for (int qt = 0; qt < 2; qt++)
#pragma unroll
        for (int dt = 0; dt < 4; dt++) Oacc[qt][dt] = (v4f){0.f,0.f,0.f,0.f};
    const v4f z = (v4f){0.f,0.f,0.f,0.f};

    for (int tt = 0; tt < ntile; tt++) {
        const int buf = tt & 1;
        __syncthreads();
        if (tt + 1 < ntile) {
            const size_t off = ((size_t)(g * 32 + tt + 1)) * 4096 + w * 1024 + lane * 8;
            const int nb = buf ^ 1;
            gll16(Kg + off,       &Ksb[nb][w * 1024]);
            gll16(Kg + off + 512, &Ksb[nb][w * 1024 + 512]);
            gll16(Vg + off,       &Vsb[nb][w * 1024]);
            gll16(Vg + off + 512, &Vsb[nb][w * 1024 + 512]);
        }
        const int t0 = tt * 64;
        const bool do0 = (t0 <= q0 + r0 + 15);
        const bool do1 = (t0 <= q0 + r0 + 31);
        if (!do1) continue;

        const unsigned short* Kb = Ksb[buf];
        const unsigned short* Vb = Vsb[buf];

        v4f sc[2][4];
#pragma unroll
        for (int jt = 0; jt < 4; jt++) {
            const int kr = (jt * 16 + n) * 64;
            v8s kf0 = *(const v8s*)&Kb[kr + (quad ^ m7) * 8];
            v8s kf1 = *(const v8s*)&Kb[kr + ((quad + 4) ^ m7) * 8];
            if (do0) {
                v4f tq = __builtin_amdgcn_mfma_f32_16x16x32_bf16(kf0, qf[0][0], z, 0, 0, 0);
                sc[0][jt] = __builtin_amdgcn_mfma_f32_16x16x32_bf16(kf1, qf[0][1], tq, 0, 0, 0);
            }
            v4f t1 = __builtin_amdgcn_mfma_f32_16x16x32_bf16(kf0, qf[1][0], z, 0, 0, 0);
            sc[1][jt] = __builtin_amdgcn_mfma_f32_16x16x32_bf16(kf1, qf[1][1], t1, 0, 0, 0);
        }

#pragma unroll
        for (int qt = 0; qt < 2; qt++) {
            if (qt == 0 && !do0) continue;
            const int qg = q0 + r0 + qt * 16 + n;
            if (t0 + 63 > q0 + r0 + qt * 16) {
#pragma unroll
                for (int jt = 0; jt < 4; jt++) {
                    const int jg = t0 + jt * 16 + quad * 4;
#pragma unroll
                    for (int reg = 0; reg < 4; reg++)
                        sc[qt][jt][reg] = (jg + reg <= qg) ? sc[qt][jt][reg] : -INFINITY;
                }
            }
#pragma unroll
            for (int jt = 0; jt < 4; jt++) {
#pragma unroll
                for (int reg = 0; reg < 4; reg++) {
                    float p = __builtin_amdgcn_exp2f(sc[qt][jt][reg]);  // 2^-inf = 0
                    sc[qt][jt][reg] = p;
                    lst[qt] += p;
                }
            }
        }

        v8s pf[2][2];
        if (do0) {
            pf[0][0] = pack8(sc[0][0], sc[0][1]);
            pf[0][1] = pack8(sc[0][2], sc[0][3]);
        }
        pf[1][0] = pack8(sc[1][0], sc[1][1]);
        pf[1][1] = pack8(sc[1][2], sc[1][3]);

#pragma unroll
        for (int dt = 0; dt < 4; dt++) {
            const int vr = (dt * 16 + n) * 64;
            v8s vf0 = *(const v8s*)&Vb[vr + (quad ^ m7) * 8];
            v8s vf1 = *(const v8s*)&Vb[vr + ((quad + 4) ^ m7) * 8];
            if (do0) {
                Oacc[0][dt] = __builtin_amdgcn_mfma_f32_16x16x32_bf16(vf0, pf[0][0], Oacc[0][dt], 0, 0, 0);
                Oacc[0][dt] = __builtin_amdgcn_mfma_f32_16x16x32_bf16(vf1, pf[0][1], Oacc[0][dt], 0, 0, 0);
            }
            Oacc[1][dt] = __builtin_amdgcn_mfma_f32_16x16x32_bf16(vf0, pf[1][0], Oacc[1][dt], 0, 0, 0);
            Oacc[1][dt] = __builtin_amdgcn_mfma_f32_16x16x32_bf16(vf1, pf[1][1], Oacc[1][dt], 0, 0, 0);
        }
    }

    unsigned short* Ohp = Oh + (size_t)g * ((size_t)SEQ * NQ);
#pragma unroll
    for (int qt = 0; qt < 2; qt++) {
        float L = lst[qt];
        L += __shfl_xor(L, 16);
        L += __shfl_xor(L, 32);
        const float inv = 0.25f / L;
        const int row = q0 + r0 + qt * 16 + n;
        unsigned short* dst = Ohp + (size_t)row * NQ + h * DH + quad * 4;
#pragma unroll
        for (int dt = 0; dt < 4; dt++) {
            uint2 pk = make_uint2(f2bf2(Oacc[qt][dt][0] * inv, Oacc[qt][dt][1] * inv),
                                  f2bf2(Oacc[qt][dt][2] * inv, Oacc[qt][dt][3] * inv));
            *(uint2*)(dst + dt * 16) = pk;
        }
    }
}

// ===========================================================================
// GEMM 2 (MFMA): out[s][o] = sum_j (sum_g Oh[g])[s][j] * Wo[o][j]. fp32 out.
// 32x64 tile, BK=64, depth-1 prefetch. Grid 64x8 = 512 blocks (2/CU).
// ===========================================================================
__global__ __launch_bounds__(256, 4) void gemm_out(
    const unsigned short* __restrict__ Oh,
    const unsigned short* __restrict__ Wob,
    float* __restrict__ C)
{
    __shared__ unsigned short Asb[32][72];
    __shared__ unsigned short Bsb[64][72];

    const int m0 = blockIdx.x * 32;
    const int n0 = blockIdx.y * 64;
    const int tid = threadIdx.x;
    const int w = tid >> 6, lane = tid & 63;
    const int n = lane & 15, quad = lane >> 4;
    const int rw = (w & 1) * 16, cw = (w >> 1) * 32;
    const int ar = tid >> 3, akc = (tid & 7) * 8;    // A: 32 rows x 8-elem chunk
    const int br = tid >> 2, bkc = (tid & 3) * 16;   // B: 64 rows x 16-elem chunk

    v4f acc[2];
    acc[0] = (v4f){0.f,0.f,0.f,0.f};
    acc[1] = (v4f){0.f,0.f,0.f,0.f};

    const size_t plane = (size_t)SEQ * NQ;
    const size_t abase = (size_t)(m0 + ar) * NQ + akc;
    const unsigned short* bp = Wob + (size_t)(n0 + br) * NQ + bkc;

    uint4 ua[4];
#pragma unroll
    for (int g = 0; g < 4; g++) ua[g] = *(const uint4*)(Oh + g * plane + abase);
    uint4 ub0 = *(const uint4*)(bp), ub1 = *(const uint4*)(bp + 8);

    for (int kb = 0; kb < NQ; kb += 64) {
        __syncthreads();
        {   // fp32-accurate 4-plane sum, single bf16 rounding
            unsigned int ow[4];
#pragma unroll
            for (int q = 0; q < 4; q++) {
                const unsigned int u0 = ((const unsigned int*)&ua[0])[q];
                const unsigned int u1 = ((const unsigned int*)&ua[1])[q];
                const unsigned int u2 = ((const unsigned int*)&ua[2])[q];
                const unsigned int u3 = ((const unsigned int*)&ua[3])[q];
                float lo = bf2f((unsigned short)(u0 & 0xffffu)) + bf2f((unsigned short)(u1 & 0xffffu))
                         + bf2f((unsigned short)(u2 & 0xffffu)) + bf2f((unsigned short)(u3 & 0xffffu));
                float hi = bf2f((unsigned short)(u0 >> 16)) + bf2f((unsigned short)(u1 >> 16))
                         + bf2f((unsigned short)(u2 >> 16)) + bf2f((unsigned short)(u3 >> 16));
                ow[q] = f2bf2(lo, hi);
            }
            *(uint4*)&Asb[ar][akc] = make_uint4(ow[0], ow[1], ow[2], ow[3]);
        }
        *(uint4*)&Bsb[br][bkc]     = ub0;
        *(uint4*)&Bsb[br][bkc + 8] = ub1;
        __syncthreads();
        if (kb + 64 < NQ) {
#pragma unroll
            for (int g = 0; g < 4; g++)
                ua[g] = *(const uint4*)(Oh + g * plane + abase + kb + 64);
            ub0 = *(const uint4*)(bp + kb + 64);
            ub1 = *(const uint4*)(bp + kb + 64 + 8);
        }
#pragma unroll
        for (int kk = 0; kk < 2; kk++) {
            v8s a  = *(const v8s*)&Asb[rw + n][kk * 32 + quad * 8];
            v8s b0 = *(const v8s*)&Bsb[cw + n][kk * 32 + quad * 8];
            v8s b1 = *(const v8s*)&Bsb[cw + 16 + n][kk * 32 + quad * 8];
            acc[0] = __builtin_amdgcn_mfma_f32_16x16x32_bf16(a, b0, acc[0], 0, 0, 0);
            acc[1] = __builtin_amdgcn_mfma_f32_16x16x32_bf16(a, b1, acc[1], 0, 0, 0);
        }
    }

#pragma unroll
    for (int ct = 0; ct < 2; ct++)
#pragma unroll
        for (int reg = 0; reg < 4; reg++) {
            const int row = m0 + rw + quad * 4 + reg;
            const int col = n0 + cw + ct * 16 + n;
            C[(size_t)row * OUTD + col] = acc[ct][reg];
        }
}

// ===========================================================================
extern "C" void kernel_launch(void* const* d_in, const int* in_sizes, int n_in,
                              void* d_out, int out_size, void* d_ws, size_t ws_size,
                              hipStream_t stream) {
    const float* x  = (const float*)d_in[0];
    const float* Wq = (const float*)d_in[1];
    const float* Wk = (const float*)d_in[2];
    const float* Wv = (const float*)d_in[3];
    const float* Wo = (const float*)d_in[4];
    float* out = (float*)d_out;

    // ws layout (bytes), 23MB total:
    //  @0:        Oh 16MB (pre-attn, the first 3.5MB doubles as xb/Wqb/Wkb/Wvb)
    //  @16777216: Qg 4MB   @20971520: Kg 1MB   @22020096: Vg 1MB
    //  @23068672: Wob 1MB  (must survive until gemm_out)
    char* base = (char*)d_ws;
    unsigned short* Oh  = (unsigned short*)(base);
    unsigned short* xb  = (unsigned short*)(base);             // dead before attn
    unsigned short* Wqb = (unsigned short*)(base + 2097152);
    unsigned short* Wkb = (unsigned short*)(base + 3145728);
    unsigned short* Wvb = (unsigned short*)(base + 3407872);
    unsigned short* Qg  = (unsigned short*)(base + 16777216);
    unsigned short* Kg  = (unsigned short*)(base + 20971520);
    unsigned short* Vg  = (unsigned short*)(base + 22020096);
    unsigned short* Wob = (unsigned short*)(base + 23068672);

    dim3 blk(256);
    cast_all<<<dim3(1152), blk, 0, stream>>>(x, Wq, Wk, Wv, Wo,
                                             xb, Wqb, Wkb, Wvb, Wob);
    gemm_qkv<<<dim3(SEQ / 64, (NQ + 2 * NKV) / 64), blk, 0, stream>>>(
        xb, Wqb, Wkb, Wvb, Qg, Kg, Vg);
    attn_mfma<<<dim3(1024), blk, 0, stream>>>(Qg, Kg, Vg, Oh);
    gemm_out<<<dim3(SEQ / 32, OUTD / 64), blk, 0, stream>>>(Oh, Wob, out);
}

// Round 13
// 142.014 us; speedup vs baseline: 1.4953x; 1.0955x over previous
//
#include <hip/hip_runtime.h>
#include <hip/hip_bf16.h>

// Problem constants
#define SEQ   2048
#define INF_  512          // IN dim
#define HQ    16           // query heads
#define KVH   4            // kv heads
#define DH    64           // head dim
#define NQ    (HQ*DH)      // 1024
#define NKV   (KVH*DH)     // 256
#define OUTD  512

typedef short v8s __attribute__((ext_vector_type(8)));   // 8 bf16 (4 VGPRs)
typedef float v4f __attribute__((ext_vector_type(4)));   // 4 fp32 acc

static __device__ __forceinline__ float bf2f(unsigned short u) {
    union { unsigned int i; float f; } c;
    c.i = ((unsigned int)u) << 16;
    return c.f;
}
static __device__ __forceinline__ unsigned short f2bf(float f) {  // RNE
    union { float f; unsigned int i; } c; c.f = f;
    unsigned int lsb = (c.i >> 16) & 1u;
    c.i += 0x7fffu + lsb;
    return (unsigned short)(c.i >> 16);
}
static __device__ __forceinline__ unsigned int f2bf2(float lo, float hi) { // packed cvt
    union { __hip_bfloat162 h; unsigned int u; } c;
    c.h = __float22bfloat162_rn(make_float2(lo, hi));
    return c.u;
}
// pack two v4f (8 fp32) into one bf16x8 fragment
static __device__ __forceinline__ v8s pack8(v4f a, v4f b) {
    union { v8s s; uint4 u; } c;
    c.u = make_uint4(f2bf2(a[0], a[1]), f2bf2(a[2], a[3]),
                     f2bf2(b[0], b[1]), f2bf2(b[2], b[3]));
    return c.s;
}

// async global->LDS DMA, 16B per lane; lds base must be lane-invariant
static __device__ __forceinline__ void gll16(const void* g, void* l) {
    __builtin_amdgcn_global_load_lds(
        (const __attribute__((address_space(1))) void*)g,
        (__attribute__((address_space(3))) void*)l, 16, 0, 0);
}

// Stage one 64x64 bf16 tile (row-major src, given row stride) into LDS with
// XOR group swizzle applied via SOURCE addresses: LDS slot s of row r holds
// k-group s^(r&7). Wave w stages rows w*16..w*16+15 (2 DMA instrs).
static __device__ __forceinline__ void stage_tile(
    const unsigned short* __restrict__ src, int stride, int kb,
    unsigned short* ldsbase, int w, int lane)
{
#pragma unroll
    for (int i = 0; i < 2; i++) {
        const int rl = w * 16 + i * 8 + (lane >> 3);
        const int kc = ((lane & 7) ^ (rl & 7)) * 8;
        gll16(src + (size_t)rl * stride + kb + kc,
              ldsbase + (w * 16 + i * 8) * 64);
    }
}

#define QSCALE 0.180336880f   // 0.125 * log2(e): scores in log2 domain -> exp2

// ===========================================================================
// Cast kernel: x/Wq/Wk/Wv/Wo fp32 -> bf16 flat copies.
// ===========================================================================
__global__ __launch_bounds__(256) void cast_all(
    const float* __restrict__ x,  const float* __restrict__ Wq,
    const float* __restrict__ Wk, const float* __restrict__ Wv,
    const float* __restrict__ Wo,
    unsigned short* __restrict__ xb,  unsigned short* __restrict__ Wqb,
    unsigned short* __restrict__ Wkb, unsigned short* __restrict__ Wvb,
    unsigned short* __restrict__ Wob)
{
    size_t i = ((size_t)blockIdx.x * 256 + threadIdx.x) * 8;
    const float* s; unsigned short* d; size_t off;
    if (i < 1048576)      { s = x;  d = xb;  off = i; }
    else if (i < 1572864) { s = Wq; d = Wqb; off = i - 1048576; }
    else if (i < 1703936) { s = Wk; d = Wkb; off = i - 1572864; }
    else if (i < 1835008) { s = Wv; d = Wvb; off = i - 1703936; }
    else                  { s = Wo; d = Wob; off = i - 1835008; }
    float4 a = *(const float4*)(s + off);
    float4 b = *(const float4*)(s + off + 4);
    *(uint4*)(d + off) = make_uint4(f2bf2(a.x, a.y), f2bf2(a.z, a.w),
                                    f2bf2(b.x, b.y), f2bf2(b.z, b.w));
}

// ===========================================================================
// GEMM 1 (MFMA): QKV projection, bf16 in -> bf16 swizzled tile buffers.
// 64x64 tile, BK=64, gll16 DMA double-buffered staging, single barrier/iter,
// zero staging VALU. Grid 32x24. Epilogue tile formats unchanged:
//   Qg[t][h], Kg[g][t]: r*64 + ((d>>3)^(r&7))*8 + (d&7)  (Q pre-scaled)
//   Vg[g][t]: d*64 + swizzled j-permuted position.
// ===========================================================================
__global__ __launch_bounds__(256, 4) void gemm_qkv(
    const unsigned short* __restrict__ xb,
    const unsigned short* __restrict__ Wqb,
    const unsigned short* __restrict__ Wkb,
    const unsigned short* __restrict__ Wvb,
    unsigned short* __restrict__ Qg,
    unsigned short* __restrict__ Kg,
    unsigned short* __restrict__ Vg)
{
    __shared__ unsigned short Asb[2][4096];
    __shared__ unsigned short Bsb[2][4096];

    const int m0 = blockIdx.x * 64;
    const int n0 = blockIdx.y * 64;

    const unsigned short* Bp; int role;   // 0=Q 1=K 2=V
    if (n0 < NQ)            { Bp = Wqb + (size_t)n0 * INF_;              role = 0; }
    else if (n0 < NQ + NKV) { Bp = Wkb + (size_t)(n0 - NQ) * INF_;       role = 1; }
    else                    { Bp = Wvb + (size_t)(n0 - NQ - NKV) * INF_; role = 2; }

    const int tid = threadIdx.x;
    const int w = tid >> 6, lane = tid & 63;
    const int n = lane & 15, quad = lane >> 4;
    const int m7 = n & 7;
    const int r0w = (w & 1) * 32, c0w = (w >> 1) * 32;
    const unsigned short* Ap = xb + (size_t)m0 * INF_;

    v4f acc[2][2];
#pragma unroll
    for (int rt = 0; rt < 2; rt++)
#pragma unroll
        for (int ct = 0; ct < 2; ct++) acc[rt][ct] = (v4f){0.f,0.f,0.f,0.f};

    stage_tile(Ap, INF_, 0, &Asb[0][0], w, lane);
    stage_tile(Bp, INF_, 0, &Bsb[0][0], w, lane);

    for (int kb = 0; kb < INF_; kb += 64) {
        const int buf = (kb >> 6) & 1;
        __syncthreads();   // drains DMA; guards buf^1 reuse
        if (kb + 64 < INF_) {
            stage_tile(Ap, INF_, kb + 64, &Asb[buf ^ 1][0], w, lane);
            stage_tile(Bp, INF_, kb + 64, &Bsb[buf ^ 1][0], w, lane);
        }
#pragma unroll
        for (int kk = 0; kk < 2; kk++) {
            const int gs = ((kk * 4 + quad) ^ m7) * 8;
            v8s a0 = *(const v8s*)&Asb[buf][(r0w + n) * 64 + gs];
            v8s a1 = *(const v8s*)&Asb[buf][(r0w + 16 + n) * 64 + gs];
            v8s b0 = *(const v8s*)&Bsb[buf][(c0w + n) * 64 + gs];
            v8s b1 = *(const v8s*)&Bsb[buf][(c0w + 16 + n) * 64 + gs];
            acc[0][0] = __builtin_amdgcn_mfma_f32_16x16x32_bf16(a0, b0, acc[0][0], 0, 0, 0);
            acc[0][1] = __builtin_amdgcn_mfma_f32_16x16x32_bf16(a0, b1, acc[0][1], 0, 0, 0);
            acc[1][0] = __builtin_amdgcn_mfma_f32_16x16x32_bf16(a1, b0, acc[1][0], 0, 0, 0);
            acc[1][1] = __builtin_amdgcn_mfma_f32_16x16x32_bf16(a1, b1, acc[1][1], 0, 0, 0);
        }
    }

    const int t = m0 >> 6;
    if (role == 0) {
        unsigned short* base = Qg + ((size_t)(t * 16 + (n0 >> 6))) * 4096;
#pragma unroll
        for (int rt = 0; rt < 2; rt++)
#pragma unroll
            for (int ct = 0; ct < 2; ct++)
#pragma unroll
                for (int reg = 0; reg < 4; reg++) {
                    const int r = r0w + rt * 16 + quad * 4 + reg;
                    const int d = c0w + ct * 16 + n;
                    base[r * 64 + (((d >> 3) ^ (r & 7)) * 8) + (d & 7)] =
                        f2bf(acc[rt][ct][reg] * QSCALE);
                }
    } else if (role == 1) {
        const int g = (n0 - NQ) >> 6;
        unsigned short* base = Kg + ((size_t)(g * 32 + t)) * 4096;
#pragma unroll
        for (int rt = 0; rt < 2; rt++)
#pragma unroll
            for (int ct = 0; ct < 2; ct++)
#pragma unroll
                for (int reg = 0; reg < 4; reg++) {
                    const int r = r0w + rt * 16 + quad * 4 + reg;
                    const int d = c0w + ct * 16 + n;
                    base[r * 64 + (((d >> 3) ^ (r & 7)) * 8) + (d & 7)] =
                        f2bf(acc[rt][ct][reg]);
                }
    } else {
        const int g = (n0 - NQ - NKV) >> 6;
        unsigned short* base = Vg + ((size_t)(g * 32 + t)) * 4096;
#pragma unroll
        for (int rt = 0; rt < 2; rt++)
#pragma unroll
            for (int ct = 0; ct < 2; ct++) {
                const int jb_ = r0w + rt * 16 + quad * 4;  // 4 consecutive j
                const int d = c0w + ct * 16 + n;
                const int p = (jb_ & 32) + (((jb_ >> 2) & 3) * 8) + (((jb_ >> 4) & 1) * 4);
                *(uint2*)&base[d * 64 + (((p >> 3) ^ (d & 7)) * 8) + (p & 7)] =
                    make_uint2(f2bf2(acc[rt][ct][0], acc[rt][ct][1]),
                               f2bf2(acc[rt][ct][2], acc[rt][ct][3]));
            }
    }
}

// ===========================================================================
// MFMA flash attention, S^T form, exp2 softmax, register-resident P^T,
// l computed by MFMA against a ones-fragment (no per-tile VALU adds, no
// end shuffles). 1024 blocks, 4/CU, LDS 32KB, 0 bank conflicts.
// ===========================================================================
__global__ __launch_bounds__(256, 4) void attn_mfma(
    const unsigned short* __restrict__ Qg,
    const unsigned short* __restrict__ Kg,
    const unsigned short* __restrict__ Vg,
    unsigned short* __restrict__ Oh)      // 4 planes of SEQ*NQ bf16
{
    __shared__ unsigned short Ksb[2][4096];
    __shared__ unsigned short Vsb[2][4096];

    const int bx = blockIdx.x;
    const int h  = bx & 15;
    const int jj = (bx >> 4) & 15;
    const int g  = bx >> 8;
    const int jj2 = (jj + 8 * (g >> 1)) & 15;
    const int qi2 = (g & 1) ? (15 - jj2) : jj2;
    const int q0 = qi2 * 128;
    const int tid = threadIdx.x;
    const int w = tid >> 6, lane = tid & 63;
    const int n = lane & 15, quad = lane >> 4;
    const int r0 = w * 32;
    const int m7 = n & 7;
    const int ntile = 2 * qi2 + 2;

    {
        const size_t off = ((size_t)(g * 32)) * 4096 + w * 1024 + lane * 8;
        gll16(Kg + off,       &Ksb[0][w * 1024]);
        gll16(Kg + off + 512, &Ksb[0][w * 1024 + 512]);
        gll16(Vg + off,       &Vsb[0][w * 1024]);
        gll16(Vg + off + 512, &Vsb[0][w * 1024 + 512]);
    }

    v8s qf[2][2];
    {
        const unsigned short* tb =
            Qg + ((size_t)((2 * qi2 + (r0 >> 6)) * 16 + h)) * 4096 + (r0 & 63) * 64;
#pragma unroll
        for (int qt = 0; qt < 2; qt++) {
            const unsigned short* rp = tb + (qt * 16 + n) * 64;
            qf[qt][0] = *(const v8s*)(rp + (quad ^ m7) * 8);
            qf[qt][1] = *(const v8s*)(rp + ((quad + 4) ^ m7) * 8);
        }
    }

    v8s ones;
#pragma unroll
    for (int i = 0; i < 8; i++) ones[i] = (short)0x3F80;  // bf16 1.0

    v4f Lacc[2];
    Lacc[0] = (v4f){0.f,0.f,0.f,0.f};
    Lacc[1] = (v4f){0.f,0.f,0.f,0.f};
    v4f Oacc[2][4];
#pragma unroll
    for (int qt = 0; qt < 2; qt++)
#pragma unroll
        for (int dt = 0; dt < 4; dt++) Oacc[qt][dt] = (v4f){0.f,0.f,0.f,0.f};
    const v4f z = (v4f){0.f,0.f,0.f,0.f};

    for (int tt = 0; tt < ntile; tt++) {
        const int buf = tt & 1;
        __syncthreads();
        if (tt + 1 < ntile) {
            const size_t off = ((size_t)(g * 32 + tt + 1)) * 4096 + w * 1024 + lane * 8;
            const int nb = buf ^ 1;
            gll16(Kg + off,       &Ksb[nb][w * 1024]);
            gll16(Kg + off + 512, &Ksb[nb][w * 1024 + 512]);
            gll16(Vg + off,       &Vsb[nb][w * 1024]);
            gll16(Vg + off + 512, &Vsb[nb][w * 1024 + 512]);
        }
        const int t0 = tt * 64;
        const bool do0 = (t0 <= q0 + r0 + 15);
        const bool do1 = (t0 <= q0 + r0 + 31);
        if (!do1) continue;

        const unsigned short* Kb = Ksb[buf];
        const unsigned short* Vb = Vsb[buf];

        // S^T = K·Q^T (C-layout: lane holds q=n, j = jt*16+quad*4+reg)
        v4f sc[2][4];
#pragma unroll
        for (int jt = 0; jt < 4; jt++) {
            const int kr = (jt * 16 + n) * 64;
            v8s kf0 = *(const v8s*)&Kb[kr + (quad ^ m7) * 8];
            v8s kf1 = *(const v8s*)&Kb[kr + ((quad + 4) ^ m7) * 8];
            if (do0) {
                v4f tq = __builtin_amdgcn_mfma_f32_16x16x32_bf16(kf0, qf[0][0], z, 0, 0, 0);
                sc[0][jt] = __builtin_amdgcn_mfma_f32_16x16x32_bf16(kf1, qf[0][1], tq, 0, 0, 0);
            }
            v4f t1 = __builtin_amdgcn_mfma_f32_16x16x32_bf16(kf0, qf[1][0], z, 0, 0, 0);
            sc[1][jt] = __builtin_amdgcn_mfma_f32_16x16x32_bf16(kf1, qf[1][1], t1, 0, 0, 0);
        }

        // mask (diagonal region only) + exp2
#pragma unroll
        for (int qt = 0; qt < 2; qt++) {
            if (qt == 0 && !do0) continue;
            const int qg = q0 + r0 + qt * 16 + n;
            if (t0 + 63 > q0 + r0 + qt * 16) {
#pragma unroll
                for (int jt = 0; jt < 4; jt++) {
                    const int jg = t0 + jt * 16 + quad * 4;
#pragma unroll
                    for (int reg = 0; reg < 4; reg++)
                        sc[qt][jt][reg] = (jg + reg <= qg) ? sc[qt][jt][reg] : -INFINITY;
                }
            }
#pragma unroll
            for (int jt = 0; jt < 4; jt++)
#pragma unroll
                for (int reg = 0; reg < 4; reg++)
                    sc[qt][jt][reg] = __builtin_amdgcn_exp2f(sc[qt][jt][reg]); // 2^-inf = 0
        }

        // P^T B-frags = C-layout registers (j-permuted PV; no LDS/shuffle)
        v8s pf[2][2];
        if (do0) {
            pf[0][0] = pack8(sc[0][0], sc[0][1]);
            pf[0][1] = pack8(sc[0][2], sc[0][3]);
        }
        pf[1][0] = pack8(sc[1][0], sc[1][1]);
        pf[1][1] = pack8(sc[1][2], sc[1][3]);

        // l-accumulation via MFMA: Lacc = 1^T · P^T  (every reg holds l_q)
        if (do0) {
            Lacc[0] = __builtin_amdgcn_mfma_f32_16x16x32_bf16(ones, pf[0][0], Lacc[0], 0, 0, 0);
            Lacc[0] = __builtin_amdgcn_mfma_f32_16x16x32_bf16(ones, pf[0][1], Lacc[0], 0, 0, 0);
        }
        Lacc[1] = __builtin_amdgcn_mfma_f32_16x16x32_bf16(ones, pf[1][0], Lacc[1], 0, 0, 0);
        Lacc[1] = __builtin_amdgcn_mfma_f32_16x16x32_bf16(ones, pf[1][1], Lacc[1], 0, 0, 0);

        // PV: O^T += V^T(permuted) · P^T
#pragma unroll
        for (int dt = 0; dt < 4; dt++) {
            const int vr = (dt * 16 + n) * 64;
            v8s vf0 = *(const v8s*)&Vb[vr + (quad ^ m7) * 8];
            v8s vf1 = *(const v8s*)&Vb[vr + ((quad + 4) ^ m7) * 8];
            if (do0) {
                Oacc[0][dt] = __builtin_amdgcn_mfma_f32_16x16x32_bf16(vf0, pf[0][0], Oacc[0][dt], 0, 0, 0);
                Oacc[0][dt] = __builtin_amdgcn_mfma_f32_16x16x32_bf16(vf1, pf[0][1], Oacc[0][dt], 0, 0, 0);
            }
            Oacc[1][dt] = __builtin_amdgcn_mfma_f32_16x16x32_bf16(vf0, pf[1][0], Oacc[1][dt], 0, 0, 0);
            Oacc[1][dt] = __builtin_amdgcn_mfma_f32_16x16x32_bf16(vf1, pf[1][1], Oacc[1][dt], 0, 0, 0);
        }
    }

    // normalize (l complete per lane in Lacc[qt][0]) & store bf16
    unsigned short* Ohp = Oh + (size_t)g * ((size_t)SEQ * NQ);
#pragma unroll
    for (int qt = 0; qt < 2; qt++) {
        const float inv = 0.25f / Lacc[qt][0];   // j=0 always unmasked -> L>0
        const int row = q0 + r0 + qt * 16 + n;
        unsigned short* dst = Ohp + (size_t)row * NQ + h * DH + quad * 4;
#pragma unroll
        for (int dt = 0; dt < 4; dt++) {
            uint2 pk = make_uint2(f2bf2(Oacc[qt][dt][0] * inv, Oacc[qt][dt][1] * inv),
                                  f2bf2(Oacc[qt][dt][2] * inv, Oacc[qt][dt][3] * inv));
            *(uint2*)(dst + dt * 16) = pk;
        }
    }
}

// ===========================================================================
// GEMM 2 (MFMA): out[s][o] = sum_j (sum_g Oh[g])[s][j] * Wo[o][j]. fp32 out.
// 32x64 tile, BK=64, depth-1 prefetch. Grid 64x8 = 512 blocks (2/CU).
// ===========================================================================
__global__ __launch_bounds__(256, 4) void gemm_out(
    const unsigned short* __restrict__ Oh,
    const unsigned short* __restrict__ Wob,
    float* __restrict__ C)
{
    __shared__ unsigned short Asb[32][72];
    __shared__ unsigned short Bsb[64][72];

    const int m0 = blockIdx.x * 32;
    const int n0 = blockIdx.y * 64;
    const int tid = threadIdx.x;
    const int w = tid >> 6, lane = tid & 63;
    const int n = lane & 15, quad = lane >> 4;
    const int rw = (w & 1) * 16, cw = (w >> 1) * 32;
    const int ar = tid >> 3, akc = (tid & 7) * 8;
    const int br = tid >> 2, bkc = (tid & 3) * 16;

    v4f acc[2];
    acc[0] = (v4f){0.f,0.f,0.f,0.f};
    acc[1] = (v4f){0.f,0.f,0.f,0.f};

    const size_t plane = (size_t)SEQ * NQ;
    const size_t abase = (size_t)(m0 + ar) * NQ + akc;
    const unsigned short* bp = Wob + (size_t)(n0 + br) * NQ + bkc;

    uint4 ua[4];
#pragma unroll
    for (int g = 0; g < 4; g++) ua[g] = *(const uint4*)(Oh + g * plane + abase);
    uint4 ub0 = *(const uint4*)(bp), ub1 = *(const uint4*)(bp + 8);

    for (int kb = 0; kb < NQ; kb += 64) {
        __syncthreads();
        {
            unsigned int ow[4];
#pragma unroll
            for (int q = 0; q < 4; q++) {
                const unsigned int u0 = ((const unsigned int*)&ua[0])[q];
                const unsigned int u1 = ((const unsigned int*)&ua[1])[q];
                const unsigned int u2 = ((const unsigned int*)&ua[2])[q];
                const unsigned int u3 = ((const unsigned int*)&ua[3])[q];
                float lo = bf2f((unsigned short)(u0 & 0xffffu)) + bf2f((unsigned short)(u1 & 0xffffu))
                         + bf2f((unsigned short)(u2 & 0xffffu)) + bf2f((unsigned short)(u3 & 0xffffu));
                float hi = bf2f((unsigned short)(u0 >> 16)) + bf2f((unsigned short)(u1 >> 16))
                         + bf2f((unsigned short)(u2 >> 16)) + bf2f((unsigned short)(u3 >> 16));
                ow[q] = f2bf2(lo, hi);
            }
            *(uint4*)&Asb[ar][akc] = make_uint4(ow[0], ow[1], ow[2], ow[3]);
        }
        *(uint4*)&Bsb[br][bkc]     = ub0;
        *(uint4*)&Bsb[br][bkc + 8] = ub1;
        __syncthreads();
        if (kb + 64 < NQ) {
#pragma unroll
            for (int g = 0; g < 4; g++)
                ua[g] = *(const uint4*)(Oh + g * plane + abase + kb + 64);
            ub0 = *(const uint4*)(bp + kb + 64);
            ub1 = *(const uint4*)(bp + kb + 64 + 8);
        }
#pragma unroll
        for (int kk = 0; kk < 2; kk++) {
            v8s a  = *(const v8s*)&Asb[rw + n][kk * 32 + quad * 8];
            v8s b0 = *(const v8s*)&Bsb[cw + n][kk * 32 + quad * 8];
            v8s b1 = *(const v8s*)&Bsb[cw + 16 + n][kk * 32 + quad * 8];
            acc[0] = __builtin_amdgcn_mfma_f32_16x16x32_bf16(a, b0, acc[0], 0, 0, 0);
            acc[1] = __builtin_amdgcn_mfma_f32_16x16x32_bf16(a, b1, acc[1], 0, 0, 0);
        }
    }

#pragma unroll
    for (int ct = 0; ct < 2; ct++)
#pragma unroll
        for (int reg = 0; reg < 4; reg++) {
            const int row = m0 + rw + quad * 4 + reg;
            const int col = n0 + cw + ct * 16 + n;
            C[(size_t)row * OUTD + col] = acc[ct][reg];
        }
}

// ===========================================================================
extern "C" void kernel_launch(void* const* d_in, const int* in_sizes, int n_in,
                              void* d_out, int out_size, void* d_ws, size_t ws_size,
                              hipStream_t stream) {
    const float* x  = (const float*)d_in[0];
    const float* Wq = (const float*)d_in[1];
    const float* Wk = (const float*)d_in[2];
    const float* Wv = (const float*)d_in[3];
    const float* Wo = (const float*)d_in[4];
    float* out = (float*)d_out;

    char* base = (char*)d_ws;
    unsigned short* Oh  = (unsigned short*)(base);
    unsigned short* xb  = (unsigned short*)(base);             // dead before attn
    unsigned short* Wqb = (unsigned short*)(base + 2097152);
    unsigned short* Wkb = (unsigned short*)(base + 3145728);
    unsigned short* Wvb = (unsigned short*)(base + 3407872);
    unsigned short* Qg  = (unsigned short*)(base + 16777216);
    unsigned short* Kg  = (unsigned short*)(base + 20971520);
    unsigned short* Vg  = (unsigned short*)(base + 22020096);
    unsigned short* Wob = (unsigned short*)(base + 23068672);

    dim3 blk(256);
    cast_all<<<dim3(1152), blk, 0, stream>>>(x, Wq, Wk, Wv, Wo,
                                             xb, Wqb, Wkb, Wvb, Wob);
    gemm_qkv<<<dim3(SEQ / 64, (NQ + 2 * NKV) / 64), blk, 0, stream>>>(
        xb, Wqb, Wkb, Wvb, Qg, Kg, Vg);
    attn_mfma<<<dim3(1024), blk, 0, stream>>>(Qg, Kg, Vg, Oh);
    gemm_out<<<dim3(SEQ / 32, OUTD / 64), blk, 0, stream>>>(Oh, Wob, out);
}